// Round 4
// baseline (343.118 us; speedup 1.0000x reference)
//
#include <hip/hip_runtime.h>
#include <math.h>

#define PI_F      3.141592653f
#define TWO_PI_F  6.283185306f
#define HALF_PI_F 1.5707963265f
#define IOU_THR_F 0.1f
#define ITILE     16

typedef unsigned long long u64;

__device__ __forceinline__ float limit_period_f(float v) {
    return v - floorf(v / TWO_PI_F + 0.5f) * TWO_PI_F;
}

__device__ __forceinline__ u64 shfl_u64(u64 v, int src) {
    unsigned int lo = (unsigned int)(v & 0xffffffffull);
    unsigned int hi = (unsigned int)(v >> 32);
    lo = __shfl((int)lo, src);
    hi = __shfl((int)hi, src);
    return ((u64)hi << 32) | (u64)lo;
}

// ---------------- Kernel 1: per-box prep (lo/hi/vol/dir) + zero indices ------
__global__ void prep_kernel(const float* __restrict__ boxes, int n,
                            float* __restrict__ lox, float* __restrict__ loy, float* __restrict__ loz,
                            float* __restrict__ hix, float* __restrict__ hiy, float* __restrict__ hiz,
                            float* __restrict__ vol, float* __restrict__ dir,
                            int* __restrict__ indices) {
    int j = blockIdx.x * blockDim.x + threadIdx.x;
    if (j >= n) return;
    float b0 = boxes[j*7+0], b1 = boxes[j*7+1], b2 = boxes[j*7+2];
    float b3 = boxes[j*7+3], b4 = boxes[j*7+4], b5 = boxes[j*7+5];
    float b6 = boxes[j*7+6];
    // reference: c = boxes[:, :3]; d = boxes[:, [5,4,3]] = (l, w, h)
    lox[j] = b0 - b5*0.5f; hix[j] = b0 + b5*0.5f;
    loy[j] = b1 - b4*0.5f; hiy[j] = b1 + b4*0.5f;
    loz[j] = b2 - b3*0.5f; hiz[j] = b2 + b3*0.5f;
    vol[j] = (b5*b4)*b3;                   // d.prod(-1) order: l*w*h
    dir[j] = limit_period_f(b6);
    indices[j] = 0;
}

// ---------------- Kernel 2: adjacency bit-matrix, i-tiled, column-word layout -
// adjC[(size_t)w * n + i] = word w of row i (bits for nodes 64w..64w+63)
__global__ void adj_kernel(const float* __restrict__ lox, const float* __restrict__ loy,
                           const float* __restrict__ loz, const float* __restrict__ hix,
                           const float* __restrict__ hiy, const float* __restrict__ hiz,
                           const float* __restrict__ vol,
                           u64* __restrict__ adjC, int n, int words) {
    __shared__ float iS[7][ITILE];
    int ib = blockIdx.x * ITILE;
    int tid = threadIdx.x;              // 256 = 4 waves
    if (tid < ITILE) {
        int i = ib + tid;
        if (i < n) {
            iS[0][tid] = lox[i]; iS[1][tid] = loy[i]; iS[2][tid] = loz[i];
            iS[3][tid] = hix[i]; iS[4][tid] = hiy[i]; iS[5][tid] = hiz[i];
            iS[6][tid] = vol[i];
        }
    }
    __syncthreads();
    int lane = tid & 63, wv = tid >> 6;
    int ntile = (n + 255) >> 8;
    for (int t = 0; t < ntile; ++t) {
        int j = (t << 8) + tid;
        bool jin = j < n;
        float ljx=0, ljy=0, ljz=0, hjx=0, hjy=0, hjz=0, vj=0;
        if (jin) {
            ljx = lox[j]; ljy = loy[j]; ljz = loz[j];
            hjx = hix[j]; hjy = hiy[j]; hjz = hiz[j];
            vj  = vol[j];
        }
        int wj = (t << 2) + wv;         // uniform across the wave
        u64 myMask = 0;
        for (int ii = 0; ii < ITILE; ++ii) {
            bool pred = false;
            if (jin && (ib + ii) < n) {
                float ix = fminf(iS[3][ii], hjx) - fmaxf(iS[0][ii], ljx); ix = fmaxf(ix, 0.0f);
                float iy = fminf(iS[4][ii], hjy) - fmaxf(iS[1][ii], ljy); iy = fmaxf(iy, 0.0f);
                float iz = fminf(iS[5][ii], hjz) - fmaxf(iS[2][ii], ljz); iz = fmaxf(iz, 0.0f);
                float inter = (ix*iy)*iz;
                float u = fmaxf(iS[6][ii] + vj - inter, 1e-8f);
                pred = (inter / u) > IOU_THR_F;
            }
            u64 mk = __ballot(pred);
            if (lane == ii) myMask = mk;
        }
        if (lane < ITILE && (ib + lane) < n && wj < words)
            adjC[(size_t)wj * n + (ib + lane)] = myMask;
    }
}

// ---------------- Kernel 3: word-sequential greedy MIS + indices push ---------
// seed(i) <=> no earlier neighbor of i is a seed (lexicographically-first MIS).
// indices[j] = cid of max-index adjacent seed, via atomicMax during the push.
__global__ void cluster_kernel(const u64* __restrict__ adjC,
                               int* __restrict__ seedListG,
                               int* __restrict__ indices,
                               int* __restrict__ nclust,
                               int n, int words) {
    __shared__ u64 eMaskS[64];     // bit i of word w: node 64w+i has earlier-word seed neighbor
    __shared__ int seedListS[64];
    __shared__ int cntS;
    int tid = threadIdx.x;         // 256
    if (tid < 64) eMaskS[tid] = 0ull;
    __syncthreads();

    u64 A = 0ull;                  // lane's own diagonal-block adjacency word
    if (tid < 64 && tid < n) A = adjC[(size_t)0 * n + tid];

    int cidBase = 0;               // maintained identically by ALL threads
    for (int w = 0; w < words; ++w) {
        // prefetch next word's diagonal block
        u64 Anext = 0ull;
        if (w + 1 < words && tid < 64) {
            int node = ((w + 1) << 6) + tid;
            if (node < n) Anext = adjC[(size_t)(w + 1) * n + node];
        }
        if (tid < 64) {            // wave 0, greedy within word w
            int base = w << 6;
            int vb = n - base;
            u64 valid = (vb >= 64) ? ~0ull : ((vb <= 0) ? 0ull : ((1ull << vb) - 1ull));
            u64 notE  = ~eMaskS[w];
            u64 avail = valid;
            u64 s = 0ull;
            u64 cand = avail & notE;
            while (cand) {         // iterations = #seeds in this word
                int b = (int)__ffsll(cand) - 1;
                s |= 1ull << b;
                u64 Ab = shfl_u64(A, b);
                avail &= ~Ab;
                u64 himask = (b >= 63) ? 0ull : ~((2ull << b) - 1ull);
                cand = avail & notE & himask;
            }
            if ((s >> tid) & 1ull) {
                int pos = __popcll(s & ((1ull << tid) - 1ull));
                seedListS[pos] = base + tid;
                seedListG[cidBase + pos] = base + tid;
            }
            if (tid == 0) cntS = __popcll(s);
        }
        __syncthreads();
        int cnt = cntS;
        // push: full row of each new seed; eMask for future words, indices for all
        int P = cnt << 6;          // cnt * 64 words
        for (int p = tid; p < P; p += 256) {
            int ci = p >> 6;
            int wi = p & 63;
            if (wi >= words) continue;
            int cid = cidBase + ci + 1;
            u64 v = adjC[(size_t)wi * n + seedListS[ci]];
            if (v) {
                if (wi > w) atomicOr(&eMaskS[wi], v);
                u64 m = v;
                while (m) {
                    int b = (int)__ffsll(m) - 1;
                    m &= m - 1;
                    atomicMax(&indices[(wi << 6) + b], cid);
                }
            }
        }
        cidBase += cnt;
        __syncthreads();
        A = Anext;
    }
    if (tid == 0) *nclust = cidBase;
}

// ---------------- Kernel 4: per-cluster fusion (seed-row member gather) -------
__global__ void fusion_kernel(const float* __restrict__ boxes,
                              const float* __restrict__ scores,
                              const int* __restrict__ indices,
                              const float* __restrict__ dir,
                              const int* __restrict__ seedListG,
                              const int* __restrict__ nclust,
                              const u64* __restrict__ adjC,
                              float* __restrict__ fused,
                              float* __restrict__ sfused,
                              int* __restrict__ validArr, int n, int words) {
    int i = blockIdx.x;           // output row; cluster id = i+1
    int lane = threadIdx.x;       // 64 = 1 wave
    int cid = i + 1;
    if (cid > *nclust) {
        if (lane < 7) fused[i*7+lane] = 0.0f;
        if (lane == 0) { sfused[i] = 0.0f; validArr[i] = 0; }
        return;
    }
    __shared__ unsigned short js[256];
    __shared__ float ms[256];
    int s = seedListG[i];
    u64 bits = (lane < words) ? adjC[(size_t)lane * n + s] : 0ull;
    // filter: keep only nodes whose final cluster is cid
    u64 keep = 0ull;
    u64 t = bits;
    while (t) {
        int b = (int)__ffsll(t) - 1;
        t &= t - 1;
        int node = (lane << 6) + b;
        if (indices[node] == cid) keep |= (1ull << b);
    }
    int cnt = __popcll(keep);
    int x = cnt;
    for (int o = 1; o < 64; o <<= 1) {
        int y = __shfl_up(x, o);
        if (lane >= o) x += y;
    }
    int excl = x - cnt;
    int m = __shfl(x, 63);
    int pos = excl;
    t = keep;
    while (t) {
        int b = (int)__ffsll(t) - 1;
        t &= t - 1;
        js[pos++] = (unsigned short)((lane << 6) + b);
    }
    __syncthreads();
    for (int k = lane; k < m; k += 64) ms[k] = scores[js[k]];
    __syncthreads();
    if (lane == 0) {
        if (m == 0) {
            for (int k = 0; k < 7; ++k) fused[i*7+k] = 0.0f;
            sfused[i] = 0.0f; validArr[i] = 0;
        } else {
            // s_sum and argmax (first occurrence of max; js ascending + strict >)
            float ssum = 0.0f, smax = -1e30f; int refj = js[0];
            for (int k = 0; k < m; ++k) {
                float sc = ms[k];
                ssum += sc;
                if (sc > smax) { smax = sc; refj = js[k]; }
            }
            float refdir = dir[refj];
            float denom = fmaxf(ssum, 1e-12f);
            float sgt = 0.0f;
            float cd0=0,cd1=0,cd2=0,cd3=0,cd4=0,cd5=0;
            for (int k = 0; k < m; ++k) {
                int j = js[k];
                float sc = ms[k];
                float d = fabsf(dir[j] - refdir);
                if (d > PI_F) d = TWO_PI_F - d;
                if (d > HALF_PI_F) sgt += sc;
                float wgt = sc / denom;
                cd0 += wgt * boxes[j*7+0];
                cd1 += wgt * boxes[j*7+1];
                cd2 += wgt * boxes[j*7+2];
                cd3 += wgt * boxes[j*7+3];
                cd4 += wgt * boxes[j*7+4];
                cd5 += wgt * boxes[j*7+5];
            }
            float sle = ssum - sgt;
            bool flipGt = (sgt <= sle);
            float ssin = 0.0f, scos = 0.0f;
            for (int k = 0; k < m; ++k) {
                int j = js[k];
                float sc = ms[k];
                float dj = dir[j];
                float d = fabsf(dj - refdir);
                if (d > PI_F) d = TWO_PI_F - d;
                bool gt = d > HALF_PI_F;
                bool flip = flipGt ? gt : !gt;
                float adj_d = limit_period_f(dj + (flip ? PI_F : 0.0f));
                float wgt = sc / denom;
                ssin += sinf(adj_d) * wgt;
                scos += cosf(adj_d) * wgt;
            }
            float theta = atan2f(ssin, scos);
            // s_fused: sort member scores descending, sum s_k^(k+1)
            for (int k = 1; k < m; ++k) {
                float key = ms[k]; int p = k - 1;
                while (p >= 0 && ms[p] < key) { ms[p+1] = ms[p]; --p; }
                ms[p+1] = key;
            }
            float sf = 0.0f;
            for (int k = 0; k < m; ++k) sf += powf(ms[k], (float)(k+1));
            sf = fminf(sf, 1.0f);
            // corners range check
            float c_ = cosf(theta), s_ = sinf(theta);
            float wdim = cd4, ldim = cd5;
            const float xs[4]  = {0.5f, 0.5f, -0.5f, -0.5f};
            const float ys_[4] = {-0.5f, 0.5f, 0.5f, -0.5f};
            bool inr = true;
            for (int c = 0; c < 4; ++c) {
                float cx = ldim * xs[c], cy = wdim * ys_[c];
                float rx = cx*c_ - cy*s_ + cd0;
                float ry = cx*s_ + cy*c_ + cd1;
                inr = inr && (rx > -140.8f) && (rx < 140.8f) && (ry > -40.0f) && (ry < 40.0f);
            }
            fused[i*7+0]=cd0; fused[i*7+1]=cd1; fused[i*7+2]=cd2;
            fused[i*7+3]=cd3; fused[i*7+4]=cd4; fused[i*7+5]=cd5;
            fused[i*7+6]=theta;
            sfused[i] = sf;
            validArr[i] = inr ? 1 : 0;
        }
    }
}

// ---------------- Kernel 5: cumsum + gated output writes ----------------
__global__ void finalize_kernel(const float* __restrict__ fused,
                                const float* __restrict__ sfused,
                                const int* __restrict__ validArr,
                                const int* __restrict__ indices,
                                float* __restrict__ out, int n) {
    __shared__ int newidS[4096];
    __shared__ unsigned char validS[4096];
    __shared__ int scanBuf[1024];
    int tid = threadIdx.x;  // 1024
    int per = (n + 1023) >> 10;  // 4
    int base = tid * per;
    int v[8];
    int sum = 0;
    for (int k = 0; k < per && k < 8; ++k) {
        int j = base + k;
        int vv = (j < n) ? validArr[j] : 0;
        v[k] = vv; sum += vv;
    }
    scanBuf[tid] = sum;
    __syncthreads();
    for (int o = 1; o < 1024; o <<= 1) {
        int val = scanBuf[tid];
        int add = (tid >= o) ? scanBuf[tid - o] : 0;
        __syncthreads();
        scanBuf[tid] = val + add;
        __syncthreads();
    }
    int run = scanBuf[tid] - sum;
    for (int k = 0; k < per && k < 8; ++k) {
        int j = base + k;
        if (j < n) { run += v[k]; newidS[j] = run; validS[j] = (unsigned char)v[k]; }
    }
    __syncthreads();
    float* boxesO  = out;
    float* scoresO = out + (size_t)7*n;
    float* validO  = out + (size_t)8*n;
    float* idxO    = out + (size_t)9*n;
    for (int j = tid; j < n; j += 1024) {
        int vv = validS[j];
        #pragma unroll
        for (int k = 0; k < 7; ++k)
            boxesO[j*7+k] = vv ? fused[j*7+k] : 0.0f;
        scoresO[j] = vv ? sfused[j] : 0.0f;
        validO[j]  = vv ? 1.0f : 0.0f;
        int ind = indices[j];
        int safe = ind - 1; if (safe < 0) safe = 0;
        bool nv = (ind > 0) && (validS[safe] != 0);
        idxO[j] = nv ? (float)newidS[safe] : 0.0f;
    }
}

extern "C" void kernel_launch(void* const* d_in, const int* in_sizes, int n_in,
                              void* d_out, int out_size, void* d_ws, size_t ws_size,
                              hipStream_t stream) {
    const float* boxes  = (const float*)d_in[0];
    const float* scores = (const float*)d_in[1];
    int n = in_sizes[0] / 7;           // 4096
    int words = (n + 63) >> 6;         // 64

    char* ws = (char*)d_ws;
    size_t nf = (size_t)n * sizeof(float);
    size_t off = 0;
    float* lox = (float*)(ws + off); off += nf;
    float* loy = (float*)(ws + off); off += nf;
    float* loz = (float*)(ws + off); off += nf;
    float* hix = (float*)(ws + off); off += nf;
    float* hiy = (float*)(ws + off); off += nf;
    float* hiz = (float*)(ws + off); off += nf;
    float* vol = (float*)(ws + off); off += nf;
    float* dir = (float*)(ws + off); off += nf;
    off = (off + 7) & ~(size_t)7;
    u64* adjC = (u64*)(ws + off);
    off += (size_t)n * words * sizeof(u64);
    int* seedList = (int*)(ws + off); off += (size_t)n * sizeof(int);
    int* indices  = (int*)(ws + off); off += (size_t)n * sizeof(int);
    float* fused  = (float*)(ws + off); off += (size_t)n * 7 * sizeof(float);
    float* sfused = (float*)(ws + off); off += nf;
    int* validArr = (int*)(ws + off); off += (size_t)n * sizeof(int);
    int* nclust   = (int*)(ws + off); off += sizeof(int);

    prep_kernel<<<(n + 255) / 256, 256, 0, stream>>>(boxes, n, lox, loy, loz,
                                                     hix, hiy, hiz, vol, dir, indices);
    adj_kernel<<<(n + ITILE - 1) / ITILE, 256, 0, stream>>>(lox, loy, loz, hix, hiy, hiz,
                                                            vol, adjC, n, words);
    cluster_kernel<<<1, 256, 0, stream>>>(adjC, seedList, indices, nclust, n, words);
    fusion_kernel<<<n, 64, 0, stream>>>(boxes, scores, indices, dir, seedList, nclust,
                                        adjC, fused, sfused, validArr, n, words);
    finalize_kernel<<<1, 1024, 0, stream>>>(fused, sfused, validArr, indices,
                                            (float*)d_out, n);
}